// Round 18
// baseline (1146.081 us; speedup 1.0000x reference)
//
#include <hip/hip_runtime.h>
#include <hip/hip_fp16.h>

#define T_TOK 16384
#define C_DIM 1024
#define F_DIM 4096
#define E_NUM 8

typedef _Float16 half8 __attribute__((ext_vector_type(8)));
typedef _Float16 half4v __attribute__((ext_vector_type(4)));
typedef float f32x4 __attribute__((ext_vector_type(4)));

// ---- workspace layout (bytes) ----
static constexpr size_t META_OFF  = 0;
static constexpr size_t XB_OFF    = 256;                                      // x fp16 [T][C]
static constexpr size_t W1T_OFF   = XB_OFF  + (size_t)2*T_TOK*C_DIM;          // w1^T fp16 [E][F][C]
static constexpr size_t W2T_OFF   = W1T_OFF + (size_t)2*E_NUM*C_DIM*F_DIM;    // w2^T fp16 [E][C][F]
static constexpr size_t HB_OFF    = W2T_OFF + (size_t)2*E_NUM*C_DIM*F_DIM;    // h fp16 [T*K][F]
static constexpr size_t YB_OFF    = HB_OFF  + (size_t)2*T_TOK*2*F_DIM;        // y fp16 [T*K][C]
static constexpr size_t TOK_OFF   = YB_OFF  + (size_t)2*T_TOK*2*C_DIM;        // int [E][T]
static constexpr size_t GATE_OFF  = TOK_OFF + (size_t)4*E_NUM*T_TOK;          // float [E][T]
static constexpr size_t TSLOT_OFF = GATE_OFF+ (size_t)4*E_NUM*T_TOK;          // int [T][2]
static constexpr size_t EPAIR_OFF = TSLOT_OFF + (size_t)4*T_TOK*2;            // int [T]
static constexpr size_t GPAIR_OFF = EPAIR_OFF + (size_t)4*T_TOK;              // float2 [T]
static constexpr size_t WS_NEED   = GPAIR_OFF + (size_t)8*T_TOK;

__device__ __forceinline__ void async16(void* lds, const void* g) {
  __builtin_amdgcn_global_load_lds((const __attribute__((address_space(1))) unsigned int*)g,
                                   (__attribute__((address_space(3))) unsigned int*)lds,
                                   16, 0, 0);
}

// de-convoy (multi-block/CU kernels only)
__device__ __forceinline__ void stagger(int bid) {
  int s = (bid >> 8) & 3;
  for (int i = 0; i < s * 5; ++i) __builtin_amdgcn_s_sleep(2);
}

// ---- transpose + cast: in fp32 [R][Cc] per expert -> out fp16 [Cc][R] ----
__global__ __launch_bounds__(256) void transpose_cast_kernel(const float* __restrict__ in,
                                                             _Float16* __restrict__ outp,
                                                             int R, int Cc) {
  __shared__ float tile[64][65];
  int e = blockIdx.z;
  const float* ip = in + (size_t)e * R * Cc;
  _Float16* op = outp + (size_t)e * R * Cc;
  int c0 = blockIdx.x * 64, r0 = blockIdx.y * 64;
  int tid = threadIdx.x;
  int lr = tid >> 4, lc = (tid & 15) * 4;
  #pragma unroll
  for (int d = 0; d < 4; ++d) {
    int row = lr + d * 16;
    float4 v = *(const float4*)(ip + (size_t)(r0 + row) * Cc + c0 + lc);
    tile[row][lc]     = v.x;
    tile[row][lc + 1] = v.y;
    tile[row][lc + 2] = v.z;
    tile[row][lc + 3] = v.w;
  }
  __syncthreads();
  int oc = tid >> 3, or8 = (tid & 7) * 8;
  #pragma unroll
  for (int d = 0; d < 2; ++d) {
    int c = oc + d * 32;
    half8 h;
    #pragma unroll
    for (int j = 0; j < 8; ++j) h[j] = (_Float16)tile[or8 + j][c];
    *(half8*)(op + (size_t)(c0 + c) * R + r0 + or8) = h;
  }
}

// ---- router (+ fused x cast): fp64 logits, top-2, NO atomics ----
__global__ __launch_bounds__(256) void router_kernel(const float* __restrict__ x,
                                                     const float* __restrict__ rw,
                                                     int* __restrict__ epair,
                                                     float2* __restrict__ gpair,
                                                     _Float16* __restrict__ xb) {
  int wv = threadIdx.x >> 6, l = threadIdx.x & 63;
  int t = blockIdx.x * 4 + wv;
  const float* xr = x + (size_t)t * C_DIM;
  double acc[E_NUM] = {};
  #pragma unroll
  for (int j = 0; j < 4; ++j) {
    float4 xv = *(const float4*)(xr + j * 256 + l * 4);
    half4v hv;
    hv[0] = (_Float16)xv.x; hv[1] = (_Float16)xv.y;
    hv[2] = (_Float16)xv.z; hv[3] = (_Float16)xv.w;
    *(half4v*)(xb + (size_t)t * C_DIM + j * 256 + l * 4) = hv;
    #pragma unroll
    for (int e = 0; e < E_NUM; ++e) {
      float4 w4 = *(const float4*)(rw + (size_t)e * C_DIM + j * 256 + l * 4);
      acc[e] += (double)xv.x * w4.x + (double)xv.y * w4.y +
                (double)xv.z * w4.z + (double)xv.w * w4.w;
    }
  }
  #pragma unroll
  for (int e = 0; e < E_NUM; ++e)
    #pragma unroll
    for (int off = 32; off; off >>= 1)
      acc[e] += __shfl_xor(acc[e], off, 64);

  if (l == 0) {
    double m = acc[0];
    #pragma unroll
    for (int e = 1; e < E_NUM; ++e) m = acc[e] > m ? acc[e] : m;
    double p[E_NUM], s = 0.0;
    #pragma unroll
    for (int e = 0; e < E_NUM; ++e) { p[e] = exp(acc[e] - m); s += p[e]; }
    int i0 = 0; double b0 = p[0];
    #pragma unroll
    for (int e = 1; e < E_NUM; ++e) if (p[e] > b0) { b0 = p[e]; i0 = e; }
    int i1 = -1; double b1v = -1.0;
    #pragma unroll
    for (int e = 0; e < E_NUM; ++e) if (e != i0 && p[e] > b1v) { b1v = p[e]; i1 = e; }
    double q0 = b0 / s, q1 = b1v / s;
    double den = q0 + q1 + 1e-9;
    epair[t] = i0 | (i1 << 8);
    gpair[t] = make_float2((float)(q0 / den), (float)(q1 / den));
  }
}

// ---- assign: per-expert ordered compaction, atomic-free ----
__global__ __launch_bounds__(1024) void assign_kernel(const int* __restrict__ epair,
                                                      const float2* __restrict__ gpair,
                                                      int* __restrict__ counts,
                                                      int* __restrict__ tok,
                                                      float* __restrict__ gate,
                                                      int* __restrict__ tslot) {
  __shared__ int wsum[16];
  __shared__ int wbase[16];
  __shared__ int stot;
  int myE = blockIdx.x;
  int tid = threadIdx.x, wid = tid >> 6, lane = tid & 63;
  int base = 0;
  for (int it = 0; it < (T_TOK * 2) / 1024; ++it) {
    int idx = it * 1024 + tid;
    int t = idx >> 1, k = idx & 1;
    int ep = epair[t];
    int e = (k ? (ep >> 8) : ep) & 0xff;
    bool f = (e == myE);
    unsigned long long mask = __ballot(f);
    int lanep = __popcll(mask & ((1ull << lane) - 1ull));
    if (lane == 0) wsum[wid] = __popcll(mask);
    __syncthreads();
    if (tid == 0) {
      int s = 0;
      #pragma unroll
      for (int i = 0; i < 16; ++i) { wbase[i] = s; s += wsum[i]; }
      stot = s;
    }
    __syncthreads();
    if (f) {
      int slot = base + wbase[wid] + lanep;
      float2 g = gpair[t];
      tok[myE * T_TOK + slot] = t;
      gate[myE * T_TOK + slot] = k ? g.y : g.x;
      tslot[idx] = (myE << 24) | slot;
    }
    base += stot;
  }
  if (tid == 0) counts[myE] = base;
}

// ---- prefix sums: rowOff meta[8..16]; 128-tileOff meta[17..25]; 256-tileOff meta[26..34] ----
__global__ void plan_kernel(int* meta) {
  if (threadIdx.x == 0 && blockIdx.x == 0) {
    int ro = 0, t128 = 0, t256 = 0;
    meta[8] = 0; meta[17] = 0; meta[26] = 0;
    for (int e = 0; e < E_NUM; ++e) {
      int c = meta[e];
      ro += c; t128 += (c + 127) >> 7; t256 += (c + 255) >> 8;
      meta[9 + e] = ro; meta[18 + e] = t128; meta[27 + e] = t256;
    }
  }
}

// ============================================================================
// gemm1: 8-phase template port, R17 + PROLOGUE DRAIN FIX.
// R17's NaN root cause: prologue issued 12 global_load_lds then iteration-0
// ph1 ds_read tile-0 with NO intervening wait (ds_read unordered vs vmem).
// Fix: vmcnt(4)+s_barrier after prologue (retires the 8 tile-0 loads, keeps
// tile-1's 4 half-tile loads in flight - never drained to 0).
// Full wait-coverage table (reads vs strictly-earlier waits), steady state:
//   ph1 reads t0-h0 (staged ph3/ph4-prev)  <- VM8@ph8-prev retires them
//   ph2-4 read t0-h1 (staged ph5/ph6-prev) <- VM6@ph1
//   ph5 reads t1-h0 (staged ph7/ph8-prev)  <- VM8@ph4
//   ph6-8 read t1-h1 (staged ph1/ph2 curr) <- VM6@ph5
// WAR: each phase's trailing barrier sequences all waves' reads (consumed
// by MFMA pre-barrier) before the slot is restaged >=1 phase later.
// gemm2 = R14-verbatim control.
// ============================================================================

#define VM4 asm volatile("s_waitcnt vmcnt(4)" ::: "memory")
#define VM6 asm volatile("s_waitcnt vmcnt(6)" ::: "memory")
#define VM8 asm volatile("s_waitcnt vmcnt(8)" ::: "memory")

#define STA(b,s,t) async16(SM + (b)*65536 + (s)*8192 + (size_t)tid*16, aSeg[s] + (t)*64)
#define STB(b,s,t) async16(SM + (b)*65536 + 32768 + (s)*8192 + (size_t)tid*16, bSeg[s] + (t)*64)

#define PH_LOAD(TB, MH, NH)                                                    \
    _Pragma("unroll")                                                          \
    for (int i2 = 0; i2 < 4; ++i2) {                                           \
      af[i2*2]   = *(const half8*)(SM + (TB) + (MH)*16384 + aOff[i2] + sw0);   \
      af[i2*2+1] = *(const half8*)(SM + (TB) + (MH)*16384 + aOff[i2] + sw1);   \
    }                                                                          \
    _Pragma("unroll")                                                          \
    for (int j2 = 0; j2 < 2; ++j2) {                                           \
      bf[j2*2]   = *(const half8*)(SM + (TB) + 32768 + (NH)*16384 + bOff[j2] + sw0); \
      bf[j2*2+1] = *(const half8*)(SM + (TB) + 32768 + (NH)*16384 + bOff[j2] + sw1); \
    }

#define PH_MMA(MH, NH)                                                         \
    __builtin_amdgcn_s_barrier();                                              \
    __builtin_amdgcn_s_setprio(1);                                             \
    _Pragma("unroll")                                                          \
    for (int i2 = 0; i2 < 4; ++i2)                                             \
      _Pragma("unroll")                                                        \
      for (int j2 = 0; j2 < 2; ++j2) {                                         \
        acc[(MH)*4+i2][(NH)*2+j2] = __builtin_amdgcn_mfma_f32_16x16x32_f16(    \
            af[i2*2], bf[j2*2], acc[(MH)*4+i2][(NH)*2+j2], 0, 0, 0);           \
        acc[(MH)*4+i2][(NH)*2+j2] = __builtin_amdgcn_mfma_f32_16x16x32_f16(    \
            af[i2*2+1], bf[j2*2+1], acc[(MH)*4+i2][(NH)*2+j2], 0, 0, 0);       \
      }                                                                        \
    __builtin_amdgcn_s_setprio(0);                                             \
    __builtin_amdgcn_s_barrier();

__global__ __launch_bounds__(512) void gemm1_kernel(const _Float16* __restrict__ xb,
                                                    const _Float16* __restrict__ w1t,
                                                    const float* __restrict__ b1,
                                                    _Float16* __restrict__ hbuf,
                                                    const int* __restrict__ tok,
                                                    const int* __restrict__ meta) {
  __shared__ _Float16 smem[65536];   // 2 bufs x (A 32K [4 segs x 64r x 128B] + B 32K)
  __shared__ int tokLds[256];

  // XCD swizzle (nwg=2176, chunk 272) + 8mt x 16nt banding
  int bid = blockIdx.x;
  int swz = (bid & 7) * 272 + (bid >> 3);
  int band = swz >> 7, rem = swz & 127;
  int nt = rem >> 3;
  int mt = band * 8 + (rem & 7);
  if (mt >= meta[26 + E_NUM]) return;
  int e = 0;
  while (mt >= meta[27 + e]) ++e;
  int ne = meta[e];
  int r0 = (mt - meta[26 + e]) << 8;
  int valid = ne - r0; if (valid > 256) valid = 256;

  int tid = threadIdx.x;
  if (tid < 256) {
    int r = tid < valid ? tid : valid - 1;
    tokLds[tid] = tok[e * T_TOK + r0 + r];
  }
  __syncthreads();

  // staging: thread -> (srow = tid>>3 in [0,64), chunk = tid&7); full 128B rows
  int srow = tid >> 3, c8 = tid & 7;
  int ch = c8 ^ (srow & 7);                    // involution
  const _Float16* aSeg[4];
  const _Float16* bSeg[4];
  #pragma unroll
  for (int s = 0; s < 4; ++s) {
    aSeg[s] = xb + (size_t)tokLds[s * 64 + srow] * C_DIM + ch * 8;
    bSeg[s] = w1t + ((size_t)e * F_DIM + nt * 256 + s * 64 + srow) * C_DIM + ch * 8;
  }
  char* SM = (char*)smem;

  // reader constants: wave w owns m = 2i + wh (i 0..7), n = 4j + wn (j 0..3)
  int w = tid >> 6, l = tid & 63;
  int wh = w >> 2, wn = w & 3;
  int rl = l & 15, q = l >> 4;
  int sw0 = (q ^ (rl & 7)) * 16;
  int sw1 = ((4 + q) ^ (rl & 7)) * 16;
  int aOff[4], bOff[2];
  #pragma unroll
  for (int i2 = 0; i2 < 4; ++i2) {
    int mq = 2 * i2 + wh;
    aOff[i2] = (mq >> 2) * 8192 + (mq & 3) * 2048 + rl * 128;
  }
  #pragma unroll
  for (int j2 = 0; j2 < 2; ++j2)
    bOff[j2] = j2 * 8192 + wn * 2048 + rl * 128;

  // prologue: tile0 full -> buf0; tile1 A-h0,B-h0 -> buf1  (12 loads)
  STA(0,0,0); STA(0,1,0); STA(0,2,0); STA(0,3,0);
  STB(0,0,0); STB(0,1,0); STB(0,2,0); STB(0,3,0);
  STA(1,0,1); STA(1,1,1); STB(1,0,1); STB(1,1,1);
  VM4;                                    // retire tile0's 8 loads (4 stay in flight)
  __builtin_amdgcn_s_barrier();

  f32x4 acc[8][4] = {};
  constexpr int NTILE = C_DIM / 64;            // 16 -> 8 iterations
  for (int p = 0; p < NTILE / 2; ++p) {
    int t1  = 2 * p + 1;
    int t0n = 2 * p + 2 < NTILE ? 2 * p + 2 : NTILE - 1;
    int t1n = 2 * p + 3 < NTILE ? 2 * p + 3 : NTILE - 1;
    half8 af[8], bf[4];
    // ph1: (0,0) of t0 (buf0)
    PH_LOAD(0, 0, 0);
    STA(1,2,t1); STA(1,3,t1);
    VM6;
    PH_MMA(0, 0);
    // ph2: (0,1) of t0
    PH_LOAD(0, 0, 1);
    STB(1,2,t1); STB(1,3,t1);
    PH_MMA(0, 1);
    // ph3: (1,0) of t0
    PH_LOAD(0, 1, 0);
    STA(0,0,t0n); STA(0,1,t0n);
    PH_MMA(1, 0);
    // ph4: (1,1) of t0
    PH_LOAD(0, 1, 1);
    STB(0,0,t0n); STB(0,1,t0n);
    VM8;
    PH_MMA(1, 1);
    // ph5: (0,0) of t1 (buf1)
    PH_LOAD(65536, 0, 0);
    STA(0,2,t0n); STA(0,3,t0n);
    VM6;
    PH_MMA(0, 0);
    // ph6: (0,1) of t1
    PH_LOAD(65536, 0, 1);
    STB(0,2,t0n); STB(0,3,t0n);
    PH_MMA(0, 1);
    // ph7: (1,0) of t1
    PH_LOAD(65536, 1, 0);
    STA(1,0,t1n); STA(1,1,t1n);
    PH_MMA(1, 0);
    // ph8: (1,1) of t1
    PH_LOAD(65536, 1, 1);
    STB(1,0,t1n); STB(1,1,t1n);
    VM8;
    PH_MMA(1, 1);
  }

  // epilogue: acc[I][J] -> row (2I+wh)*16 + q*4 + r, col nt*256 + (4J+wn)*16 + rl
  int hbase = meta[8 + e] + r0;
  float bv[4];
  #pragma unroll
  for (int J = 0; J < 4; ++J)
    bv[J] = b1[(size_t)e * F_DIM + nt * 256 + (4 * J + wn) * 16 + rl];
  #pragma unroll
  for (int I = 0; I < 8; ++I) {
    int rb = (2 * I + wh) * 16 + q * 4;
    #pragma unroll
    for (int J = 0; J < 4; ++J) {
      int col = nt * 256 + (4 * J + wn) * 16 + rl;
      #pragma unroll
      for (int r = 0; r < 4; ++r) {
        int row = rb + r;
        if (row < valid) {
          float pre = acc[I][J][r] + bv[J];
          float g = 0.5f * pre * (1.0f + erff(pre * 0.70710678118654752f));
          hbuf[(size_t)(hbase + row) * F_DIM + col] = (_Float16)g;
        }
      }
    }
  }
}

// ---- grouped GEMM2 (R14-verbatim): 128x256, BK=64, 8 waves, 2-barrier ----
__global__ __launch_bounds__(512) void gemm2_kernel(const _Float16* __restrict__ hbuf,
                                                    const _Float16* __restrict__ w2t,
                                                    const float* __restrict__ b2,
                                                    _Float16* __restrict__ ybuf,
                                                    const float* __restrict__ gate,
                                                    const int* __restrict__ meta) {
  __shared__ _Float16 smem[24576];   // A 16 KB + B 32 KB
  __shared__ float gateLds[128];

  int bid = blockIdx.x;
  int swz = (bid & 7) * 132 + (bid >> 3);
  int band = swz >> 5, rem = swz & 31;
  int nt = rem >> 3;
  int mt = band * 8 + (rem & 7);
  if (mt >= meta[17 + E_NUM]) return;
  stagger(bid);
  int e = 0;
  while (mt >= meta[18 + e]) ++e;
  int ne = meta[e];
  int r0 = (mt - meta[17 + e]) << 7;
  int valid = ne - r0; if (valid > 128) valid = 128;
  int hbase = meta[8 + e] + r0;

  int tid = threadIdx.x;
  if (tid < 128) {
    int r = tid < valid ? tid : valid - 1;
    gateLds[tid] = gate[e * T_TOK + r0 + r];
  }
  __syncthreads();

  int srow = tid >> 3, c8 = tid & 7;
  int ch = c8 ^ (srow & 7);
  int rcLo = srow      < valid ? srow      : valid - 1;
  int rcHi = srow + 64 < valid ? srow + 64 : valid - 1;
  const _Float16* aLo = hbuf + (size_t)(hbase + rcLo) * F_DIM + ch * 8;
  const _Float16* aHi = hbuf + (size_t)(hbase + rcHi) * F_DIM + ch * 8;
  const _Float16* bS  = w2t + ((size_t)e * C_DIM + nt * 256 + srow) * F_DIM + ch * 8;

  char* SM = (char*)smem;
  char* dst = SM + (size_t)tid * 16;

  int w = tid >> 6, l = tid & 63;
  int wm = w >> 2, wn = w & 3;
  int rl = l & 15, q = l >> 4;
  int sw0 = (q ^ (rl & 7)) * 16;
  int sw1 = ((4 + q) ^ (rl & 7)) * 16;
  int aBy = wm * 8192 + rl * 128;
  int bBy = 16384 + wn * 8192 + rl * 128;

  f32x4 acc[4][4] = {};
  constexpr int NT = F_DIM / 64;   // 64
  for (int kt = 0; kt < NT; ++kt) {
    __syncthreads();
    int ko = kt * 64;
    async16(dst,          aLo + ko);
    async16(dst + 8192,   aHi + ko);
    async16(dst + 16384,  bS + ko);
    async16(dst + 24576,  bS + (size_t) 64 * F_DIM + ko);
    async16(dst + 32768,  bS + (size_t)128 * F_DIM + ko);
    async16(dst + 40960,  bS + (size_t)192 * F_DIM + ko);
    __syncthreads();
    #pragma unroll
    for (int ks = 0; ks < 2; ++ks) {
      int sw = ks ? sw1 : sw0;
      half8 af[4], bf[4];
      #pragma unroll
      for (int m = 0; m < 4; ++m)
        af[m] = *(const half8*)(SM + aBy + m * 2048 + sw);
      #pragma unroll
      for (int n = 0; n < 4; ++n)
        bf[n] = *(const half8*)(SM + bBy + n * 2048 + sw);
      #pragma unroll
      for (int m = 0; m < 4; ++m)
        #pragma unroll
        for (int n = 0; n < 4; ++n)
          acc[m][n] = __builtin_amdgcn_mfma_f32_16x16x32_f16(af[m], bf[n], acc[m][n], 0, 0, 0);
    }
  }

  float bv[4];
  #pragma unroll
  for (int n = 0; n < 4; ++n)
    bv[n] = b2[(size_t)e * C_DIM + nt * 256 + wn * 64 + n * 16 + rl];
  #pragma unroll
  for (int m = 0; m < 4; ++m) {
    int rb = wm * 64 + m * 16 + q * 4;
    #pragma unroll
    for (int n = 0; n < 4; ++n) {
      int col = nt * 256 + wn * 64 + n * 16 + rl;
      #pragma unroll
      for (int r = 0; r < 4; ++r) {
        int rr = rb + r;
        if (rr < valid) {
          float val = gateLds[rr] * (acc[m][n][r] + bv[n]);
          ybuf[(size_t)(hbase + rr) * C_DIM + col] = (_Float16)val;
        }
      }
    }
  }
}

// ---- combine: out[t] = y(slot0) + y(slot1) ----
__global__ __launch_bounds__(256) void combine_kernel(const _Float16* __restrict__ ybuf,
                                                      const int* __restrict__ tslot,
                                                      const int* __restrict__ meta,
                                                      float* __restrict__ out) {
  int gid = blockIdx.x * 256 + threadIdx.x;
  int t = gid >> 7;
  int cc = (gid & 127) << 3;
  int s0 = tslot[t * 2], s1 = tslot[t * 2 + 1];
  size_t r0 = (size_t)meta[8 + (s0 >> 24)] + (s0 & 0xFFFFFF);
  size_t r1 = (size_t)meta[8 + (s1 >> 24)] + (s1 & 0xFFFFFF);
  half8 y0 = *(const half8*)(ybuf + r0 * C_DIM + cc);
  half8 y1 = *(const half8*)(ybuf + r1 * C_DIM + cc);
  float4 o0, o1;
  o0.x = (float)y0[0] + (float)y1[0];
  o0.y = (float)y0[1] + (float)y1[1];
  o0.z = (float)y0[2] + (float)y1[2];
  o0.w = (float)y0[3] + (float)y1[3];
  o1.x = (float)y0[4] + (float)y1[4];
  o1.y = (float)y0[5] + (float)y1[5];
  o1.z = (float)y0[6] + (float)y1[6];
  o1.w = (float)y0[7] + (float)y1[7];
  *(float4*)(out + (size_t)t * C_DIM + cc) = o0;
  *(float4*)(out + (size_t)t * C_DIM + cc + 4) = o1;
}

extern "C" void kernel_launch(void* const* d_in, const int* in_sizes, int n_in,
                              void* d_out, int out_size, void* d_ws, size_t ws_size,
                              hipStream_t stream) {
  (void)in_sizes; (void)n_in; (void)out_size;
  if (!d_ws || ws_size < WS_NEED) return;  // need ~481 MiB scratch

  const float* x  = (const float*)d_in[0];
  const float* rw = (const float*)d_in[1];
  const float* w1 = (const float*)d_in[2];
  const float* b1 = (const float*)d_in[3];
  const float* w2 = (const float*)d_in[4];
  const float* b2 = (const float*)d_in[5];
  float* out = (float*)d_out;

  char* ws = (char*)d_ws;
  int*       meta  = (int*)(ws + META_OFF);
  _Float16*  xb    = (_Float16*)(ws + XB_OFF);
  _Float16*  w1t   = (_Float16*)(ws + W1T_OFF);
  _Float16*  w2t   = (_Float16*)(ws + W2T_OFF);
  _Float16*  hbuf  = (_Float16*)(ws + HB_OFF);
  _Float16*  ybuf  = (_Float16*)(ws + YB_OFF);
  int*       tok   = (int*)(ws + TOK_OFF);
  float*     gate  = (float*)(ws + GATE_OFF);
  int*       tslot = (int*)(ws + TSLOT_OFF);
  int*       epair = (int*)(ws + EPAIR_OFF);
  float2*    gpair = (float2*)(ws + GPAIR_OFF);

  hipMemsetAsync(meta, 0, 256, stream);

  transpose_cast_kernel<<<dim3(F_DIM / 64, C_DIM / 64, E_NUM), 256, 0, stream>>>(w1, w1t, C_DIM, F_DIM);
  transpose_cast_kernel<<<dim3(C_DIM / 64, F_DIM / 64, E_NUM), 256, 0, stream>>>(w2, w2t, F_DIM, C_DIM);
  router_kernel<<<T_TOK / 4, 256, 0, stream>>>(x, rw, epair, gpair, xb);
  assign_kernel<<<E_NUM, 1024, 0, stream>>>(epair, gpair, meta, tok, gate, tslot);
  plan_kernel<<<1, 64, 0, stream>>>(meta);

  // gemm1: max 256-row M-tiles = T*K/256 + E = 136 -> 136*16 = 2176 (%8==0)
  gemm1_kernel<<<136 * 16, 512, 0, stream>>>(xb, w1t, b1, hbuf, tok, meta);
  // gemm2: max 128-row M-tiles = 263 -> 264 x 4 nt = 1056 (%8==0)
  gemm2_kernel<<<264 * 4, 512, 0, stream>>>(hbuf, w2t, b2, ybuf, gate, meta);
  combine_kernel<<<(T_TOK * (C_DIM / 8)) / 256, 256, 0, stream>>>(ybuf, tslot, meta, out);
}

// Round 19
// 934.289 us; speedup vs baseline: 1.2267x; 1.2267x over previous
//
#include <hip/hip_runtime.h>
#include <hip/hip_fp16.h>

#define T_TOK 16384
#define C_DIM 1024
#define F_DIM 4096
#define E_NUM 8

typedef _Float16 half8 __attribute__((ext_vector_type(8)));
typedef _Float16 half4v __attribute__((ext_vector_type(4)));
typedef float f32x4 __attribute__((ext_vector_type(4)));

// ---- workspace layout (bytes) ----
static constexpr size_t META_OFF  = 0;
static constexpr size_t XB_OFF    = 256;                                      // x fp16 [T][C]
static constexpr size_t W1T_OFF   = XB_OFF  + (size_t)2*T_TOK*C_DIM;          // w1^T fp16 [E][F][C]
static constexpr size_t W2T_OFF   = W1T_OFF + (size_t)2*E_NUM*C_DIM*F_DIM;    // w2^T fp16 [E][C][F]
static constexpr size_t HB_OFF    = W2T_OFF + (size_t)2*E_NUM*C_DIM*F_DIM;    // h fp16 [T*K][F]
static constexpr size_t YB_OFF    = HB_OFF  + (size_t)2*T_TOK*2*F_DIM;        // y fp16 [T*K][C]
static constexpr size_t TOK_OFF   = YB_OFF  + (size_t)2*T_TOK*2*C_DIM;        // int [E][T]
static constexpr size_t GATE_OFF  = TOK_OFF + (size_t)4*E_NUM*T_TOK;          // float [E][T]
static constexpr size_t TSLOT_OFF = GATE_OFF+ (size_t)4*E_NUM*T_TOK;          // int [T][2]
static constexpr size_t EPAIR_OFF = TSLOT_OFF + (size_t)4*T_TOK*2;            // int [T]   e0|(e1<<8)
static constexpr size_t GPAIR_OFF = EPAIR_OFF + (size_t)4*T_TOK;              // float2 [T]
static constexpr size_t WS_NEED   = GPAIR_OFF + (size_t)8*T_TOK;

__device__ __forceinline__ void async16(void* lds, const void* g) {
  __builtin_amdgcn_global_load_lds((const __attribute__((address_space(1))) unsigned int*)g,
                                   (__attribute__((address_space(3))) unsigned int*)lds,
                                   16, 0, 0);
}

// de-convoy: phase-shift co-resident blocks
__device__ __forceinline__ void stagger(int bid) {
  int s = (bid >> 8) & 3;
  for (int i = 0; i < s * 5; ++i) __builtin_amdgcn_s_sleep(2);  // ~s*640 cyc
}

// ---- transpose + cast: in fp32 [R][Cc] per expert -> out fp16 [Cc][R] ----
__global__ __launch_bounds__(256) void transpose_cast_kernel(const float* __restrict__ in,
                                                             _Float16* __restrict__ outp,
                                                             int R, int Cc) {
  __shared__ float tile[64][65];
  int e = blockIdx.z;
  const float* ip = in + (size_t)e * R * Cc;
  _Float16* op = outp + (size_t)e * R * Cc;
  int c0 = blockIdx.x * 64, r0 = blockIdx.y * 64;
  int tid = threadIdx.x;
  int lr = tid >> 4, lc = (tid & 15) * 4;
  #pragma unroll
  for (int d = 0; d < 4; ++d) {
    int row = lr + d * 16;
    float4 v = *(const float4*)(ip + (size_t)(r0 + row) * Cc + c0 + lc);
    tile[row][lc]     = v.x;
    tile[row][lc + 1] = v.y;
    tile[row][lc + 2] = v.z;
    tile[row][lc + 3] = v.w;
  }
  __syncthreads();
  int oc = tid >> 3, or8 = (tid & 7) * 8;
  #pragma unroll
  for (int d = 0; d < 2; ++d) {
    int c = oc + d * 32;
    half8 h;
    #pragma unroll
    for (int j = 0; j < 8; ++j) h[j] = (_Float16)tile[or8 + j][c];
    *(half8*)(op + (size_t)(c0 + c) * R + r0 + or8) = h;
  }
}

// ---- router (+ fused x fp32->fp16 cast): fp64 logits, top-2, NO atomics ----
__global__ __launch_bounds__(256) void router_kernel(const float* __restrict__ x,
                                                     const float* __restrict__ rw,
                                                     int* __restrict__ epair,
                                                     float2* __restrict__ gpair,
                                                     _Float16* __restrict__ xb) {
  int wv = threadIdx.x >> 6, l = threadIdx.x & 63;
  int t = blockIdx.x * 4 + wv;
  const float* xr = x + (size_t)t * C_DIM;
  double acc[E_NUM] = {};
  #pragma unroll
  for (int j = 0; j < 4; ++j) {
    float4 xv = *(const float4*)(xr + j * 256 + l * 4);
    half4v hv;
    hv[0] = (_Float16)xv.x; hv[1] = (_Float16)xv.y;
    hv[2] = (_Float16)xv.z; hv[3] = (_Float16)xv.w;
    *(half4v*)(xb + (size_t)t * C_DIM + j * 256 + l * 4) = hv;
    #pragma unroll
    for (int e = 0; e < E_NUM; ++e) {
      float4 w4 = *(const float4*)(rw + (size_t)e * C_DIM + j * 256 + l * 4);
      acc[e] += (double)xv.x * w4.x + (double)xv.y * w4.y +
                (double)xv.z * w4.z + (double)xv.w * w4.w;
    }
  }
  #pragma unroll
  for (int e = 0; e < E_NUM; ++e)
    #pragma unroll
    for (int off = 32; off; off >>= 1)
      acc[e] += __shfl_xor(acc[e], off, 64);

  if (l == 0) {
    double m = acc[0];
    #pragma unroll
    for (int e = 1; e < E_NUM; ++e) m = acc[e] > m ? acc[e] : m;
    double p[E_NUM], s = 0.0;
    #pragma unroll
    for (int e = 0; e < E_NUM; ++e) { p[e] = exp(acc[e] - m); s += p[e]; }
    int i0 = 0; double b0 = p[0];
    #pragma unroll
    for (int e = 1; e < E_NUM; ++e) if (p[e] > b0) { b0 = p[e]; i0 = e; }
    int i1 = -1; double b1v = -1.0;
    #pragma unroll
    for (int e = 0; e < E_NUM; ++e) if (e != i0 && p[e] > b1v) { b1v = p[e]; i1 = e; }
    double q0 = b0 / s, q1 = b1v / s;
    double den = q0 + q1 + 1e-9;
    epair[t] = i0 | (i1 << 8);
    gpair[t] = make_float2((float)(q0 / den), (float)(q1 / den));
  }
}

// ---- assign: per-expert ordered compaction, atomic-free (R7-proven) ----
__global__ __launch_bounds__(1024) void assign_kernel(const int* __restrict__ epair,
                                                      const float2* __restrict__ gpair,
                                                      int* __restrict__ counts,
                                                      int* __restrict__ tok,
                                                      float* __restrict__ gate,
                                                      int* __restrict__ tslot) {
  __shared__ int wsum[16];
  __shared__ int wbase[16];
  __shared__ int stot;
  int myE = blockIdx.x;
  int tid = threadIdx.x, wid = tid >> 6, lane = tid & 63;
  int base = 0;
  for (int it = 0; it < (T_TOK * 2) / 1024; ++it) {
    int idx = it * 1024 + tid;
    int t = idx >> 1, k = idx & 1;
    int ep = epair[t];
    int e = (k ? (ep >> 8) : ep) & 0xff;
    bool f = (e == myE);
    unsigned long long mask = __ballot(f);
    int lanep = __popcll(mask & ((1ull << lane) - 1ull));
    if (lane == 0) wsum[wid] = __popcll(mask);
    __syncthreads();
    if (tid == 0) {
      int s = 0;
      #pragma unroll
      for (int i = 0; i < 16; ++i) { wbase[i] = s; s += wsum[i]; }
      stot = s;
    }
    __syncthreads();
    if (f) {
      int slot = base + wbase[wid] + lanep;
      float2 g = gpair[t];
      tok[myE * T_TOK + slot] = t;
      gate[myE * T_TOK + slot] = k ? g.y : g.x;
      tslot[idx] = (myE << 24) | slot;
    }
    base += stot;
  }
  if (tid == 0) counts[myE] = base;
}

// ---- prefix sums: rowOff meta[8..16]; 128-row tileOff meta[17..25] ----
__global__ void plan_kernel(int* meta) {
  if (threadIdx.x == 0 && blockIdx.x == 0) {
    int ro = 0, t128 = 0;
    meta[8] = 0; meta[17] = 0;
    for (int e = 0; e < E_NUM; ++e) {
      int c = meta[e];
      ro += c; t128 += (c + 127) >> 7;
      meta[9 + e] = ro; meta[18 + e] = t128;
    }
  }
}

// ============================================================================
// FINAL = R14/R16 (session best, 934us). The 8-phase family is conclusively
// null here (R18 faithful port w/ verified wait coverage: 662us vs 415us —
// 4th falsification; at 1 blk/CU the 16-barrier lockstep costs more than
// counted-vmcnt recovers; 2-barrier + 3 blk/CU gets overlap free via m114).
// Verified-in: fp16 MFMA + fp64 router (absmax 3.6x under threshold),
// atomic-free routing (R7, -340us), involution swizzle (R2, conflicts
// 1e8->0), full-row 128B staging (R14, halves line transactions, +5%),
// XCD banding + stagger (R11), natural occupancy (launch_bounds waves/EU
// spills: R4, R15). gemm1 = 661 TF = 2-phase parity w/ guide ref (m230).
// ============================================================================

// ---- grouped GEMM1: h = gelu(x[tok] @ w1[e] + b1[e]) ----
// 128x256 tile, BK=64, 8 waves (2M x 4N), LDS 48.5 KiB.
__global__ __launch_bounds__(512) void gemm1_kernel(const _Float16* __restrict__ xb,
                                                    const _Float16* __restrict__ w1t,
                                                    const float* __restrict__ b1,
                                                    _Float16* __restrict__ hbuf,
                                                    const int* __restrict__ tok,
                                                    const int* __restrict__ meta) {
  __shared__ _Float16 smem[24576];   // A 16 KB [128r][128B] + B 32 KB [256r][128B]
  __shared__ int tokLds[128];

  int bid = blockIdx.x;
  int swz = (bid & 7) * 528 + (bid >> 3);
  int band = swz >> 7, rem = swz & 127;
  int nt = rem >> 3;
  int mt = band * 8 + (rem & 7);
  if (mt >= meta[17 + E_NUM]) return;
  stagger(bid);
  int e = 0;
  while (mt >= meta[18 + e]) ++e;
  int ne = meta[e];
  int r0 = (mt - meta[17 + e]) << 7;
  int valid = ne - r0; if (valid > 128) valid = 128;

  int tid = threadIdx.x;
  if (tid < 128) {
    int r = tid < valid ? tid : valid - 1;
    tokLds[tid] = tok[e * T_TOK + r0 + r];
  }
  __syncthreads();

  // staging: thread -> (row = tid>>3 [0..63], chunk = tid&7); full 128B rows
  int srow = tid >> 3, c8 = tid & 7;
  int ch = c8 ^ (srow & 7);                    // involution; (srow+64k)&7 == srow&7
  const _Float16* aLo = xb + (size_t)tokLds[srow] * C_DIM + ch * 8;
  const _Float16* aHi = xb + (size_t)tokLds[srow + 64] * C_DIM + ch * 8;
  const _Float16* bS  = w1t + ((size_t)e * F_DIM + nt * 256 + srow) * C_DIM + ch * 8;

  char* SM = (char*)smem;
  char* dst = SM + (size_t)tid * 16;   // linear: srow*128 + c8*16 == tid*16

  int w = tid >> 6, l = tid & 63;
  int wm = w >> 2, wn = w & 3;
  int rl = l & 15, q = l >> 4;
  int sw0 = (q ^ (rl & 7)) * 16;         // ks0 chunks 0-3
  int sw1 = ((4 + q) ^ (rl & 7)) * 16;   // ks1 chunks 4-7
  int aBy = wm * 8192 + rl * 128;              // + m*2048 + sw
  int bBy = 16384 + wn * 8192 + rl * 128;      // + n*2048 + sw

  f32x4 acc[4][4] = {};
  constexpr int NT = C_DIM / 64;   // 16
  for (int kt = 0; kt < NT; ++kt) {
    __syncthreads();
    int ko = kt * 64;
    async16(dst,          aLo + ko);                     // A rows 0-63
    async16(dst + 8192,   aHi + ko);                     // A rows 64-127
    async16(dst + 16384,  bS + ko);                      // B rows 0-63
    async16(dst + 24576,  bS + (size_t) 64 * C_DIM + ko);// B rows 64-127
    async16(dst + 32768,  bS + (size_t)128 * C_DIM + ko);// B rows 128-191
    async16(dst + 40960,  bS + (size_t)192 * C_DIM + ko);// B rows 192-255
    __syncthreads();
    #pragma unroll
    for (int ks = 0; ks < 2; ++ks) {
      int sw = ks ? sw1 : sw0;
      half8 af[4], bf[4];
      #pragma unroll
      for (int m = 0; m < 4; ++m)
        af[m] = *(const half8*)(SM + aBy + m * 2048 + sw);
      #pragma unroll
      for (int n = 0; n < 4; ++n)
        bf[n] = *(const half8*)(SM + bBy + n * 2048 + sw);
      #pragma unroll
      for (int m = 0; m < 4; ++m)
        #pragma unroll
        for (int n = 0; n < 4; ++n)
          acc[m][n] = __builtin_amdgcn_mfma_f32_16x16x32_f16(af[m], bf[n], acc[m][n], 0, 0, 0);
    }
  }

  int hbase = meta[8 + e] + r0;
  float bv[4];
  #pragma unroll
  for (int n = 0; n < 4; ++n)
    bv[n] = b1[(size_t)e * F_DIM + nt * 256 + wn * 64 + n * 16 + rl];
  #pragma unroll
  for (int m = 0; m < 4; ++m) {
    int rb = wm * 64 + m * 16 + q * 4;
    #pragma unroll
    for (int n = 0; n < 4; ++n) {
      int col = nt * 256 + wn * 64 + n * 16 + rl;
      #pragma unroll
      for (int r = 0; r < 4; ++r) {
        int rr = rb + r;
        if (rr < valid) {
          float pre = acc[m][n][r] + bv[n];
          float g = 0.5f * pre * (1.0f + erff(pre * 0.70710678118654752f));
          hbuf[(size_t)(hbase + rr) * F_DIM + col] = (_Float16)g;
        }
      }
    }
  }
}

// ---- grouped GEMM2: ybuf = gate * (h @ w2[e] + b2[e]) ----
// Same 128x256/8-wave structure; A = hbuf (contiguous rows), B = w2t.
__global__ __launch_bounds__(512) void gemm2_kernel(const _Float16* __restrict__ hbuf,
                                                    const _Float16* __restrict__ w2t,
                                                    const float* __restrict__ b2,
                                                    _Float16* __restrict__ ybuf,
                                                    const float* __restrict__ gate,
                                                    const int* __restrict__ meta) {
  __shared__ _Float16 smem[24576];   // A 16 KB + B 32 KB
  __shared__ float gateLds[128];

  // XCD swizzle (nwg=1056, chunk 132) + 8mt x 4nt banding
  int bid = blockIdx.x;
  int swz = (bid & 7) * 132 + (bid >> 3);
  int band = swz >> 5, rem = swz & 31;
  int nt = rem >> 3;
  int mt = band * 8 + (rem & 7);
  if (mt >= meta[17 + E_NUM]) return;
  stagger(bid);
  int e = 0;
  while (mt >= meta[18 + e]) ++e;
  int ne = meta[e];
  int r0 = (mt - meta[17 + e]) << 7;
  int valid = ne - r0; if (valid > 128) valid = 128;
  int hbase = meta[8 + e] + r0;

  int tid = threadIdx.x;
  if (tid < 128) {
    int r = tid < valid ? tid : valid - 1;
    gateLds[tid] = gate[e * T_TOK + r0 + r];
  }
  __syncthreads();

  int srow = tid >> 3, c8 = tid & 7;
  int ch = c8 ^ (srow & 7);
  int rcLo = srow      < valid ? srow      : valid - 1;
  int rcHi = srow + 64 < valid ? srow + 64 : valid - 1;
  const _Float16* aLo = hbuf + (size_t)(hbase + rcLo) * F_DIM + ch * 8;
  const _Float16* aHi = hbuf + (size_t)(hbase + rcHi) * F_DIM + ch * 8;
  const _Float16* bS  = w2t + ((size_t)e * C_DIM + nt * 256 + srow) * F_DIM + ch * 8;

  char* SM = (char*)smem;
  char* dst = SM + (size_t)tid * 16;

  int w = tid >> 6, l = tid & 63;
  int wm = w >> 2, wn = w & 3;
  int rl = l & 15, q = l >> 4;
  int sw0 = (q ^ (rl & 7)) * 16;
  int sw1 = ((4 + q) ^ (rl & 7)) * 16;
  int aBy = wm * 8192 + rl * 128;
  int bBy = 16384 + wn * 8192 + rl * 128;

  f32x4 acc[4][4] = {};
  constexpr int NT = F_DIM / 64;   // 64
  for (int kt = 0; kt < NT; ++kt) {
    __syncthreads();
    int ko = kt * 64;
    async16(dst,          aLo + ko);
    async16(dst + 8192,   aHi + ko);
    async16(dst + 16384,  bS + ko);
    async16(dst + 24576,  bS + (size_t) 64 * F_DIM + ko);
    async16(dst + 32768,  bS + (size_t)128 * F_DIM + ko);
    async16(dst + 40960,  bS + (size_t)192 * F_DIM + ko);
    __syncthreads();
    #pragma unroll
    for (int ks = 0; ks < 2; ++ks) {
      int sw = ks ? sw1 : sw0;
      half8 af[4], bf[4];
      #pragma unroll
      for (int m = 0; m < 4; ++m)
        af[m] = *(const half8*)(SM + aBy + m * 2048 + sw);
      #pragma unroll
      for (int n = 0; n < 4; ++n)
        bf[n] = *(const half8*)(SM + bBy + n * 2048 + sw);
      #pragma unroll
      for (int m = 0; m < 4; ++m)
        #pragma unroll
        for (int n = 0; n < 4; ++n)
          acc[m][n] = __builtin_amdgcn_mfma_f32_16x16x32_f16(af[m], bf[n], acc[m][n], 0, 0, 0);
    }
  }

  float bv[4];
  #pragma unroll
  for (int n = 0; n < 4; ++n)
    bv[n] = b2[(size_t)e * C_DIM + nt * 256 + wn * 64 + n * 16 + rl];
  #pragma unroll
  for (int m = 0; m < 4; ++m) {
    int rb = wm * 64 + m * 16 + q * 4;
    #pragma unroll
    for (int n = 0; n < 4; ++n) {
      int col = nt * 256 + wn * 64 + n * 16 + rl;
      #pragma unroll
      for (int r = 0; r < 4; ++r) {
        int rr = rb + r;
        if (rr < valid) {
          float val = gateLds[rr] * (acc[m][n][r] + bv[n]);
          ybuf[(size_t)(hbase + rr) * C_DIM + col] = (_Float16)val;
        }
      }
    }
  }
}

// ---- combine: out[t] = y(slot0) + y(slot1) ----
__global__ __launch_bounds__(256) void combine_kernel(const _Float16* __restrict__ ybuf,
                                                      const int* __restrict__ tslot,
                                                      const int* __restrict__ meta,
                                                      float* __restrict__ out) {
  int gid = blockIdx.x * 256 + threadIdx.x;
  int t = gid >> 7;
  int cc = (gid & 127) << 3;
  int s0 = tslot[t * 2], s1 = tslot[t * 2 + 1];
  size_t r0 = (size_t)meta[8 + (s0 >> 24)] + (s0 & 0xFFFFFF);
  size_t r1 = (size_t)meta[8 + (s1 >> 24)] + (s1 & 0xFFFFFF);
  half8 y0 = *(const half8*)(ybuf + r0 * C_DIM + cc);
  half8 y1 = *(const half8*)(ybuf + r1 * C_DIM + cc);
  float4 o0, o1;
  o0.x = (float)y0[0] + (float)y1[0];
  o0.y = (float)y0[1] + (float)y1[1];
  o0.z = (float)y0[2] + (float)y1[2];
  o0.w = (float)y0[3] + (float)y1[3];
  o1.x = (float)y0[4] + (float)y1[4];
  o1.y = (float)y0[5] + (float)y1[5];
  o1.z = (float)y0[6] + (float)y1[6];
  o1.w = (float)y0[7] + (float)y1[7];
  *(float4*)(out + (size_t)t * C_DIM + cc) = o0;
  *(float4*)(out + (size_t)t * C_DIM + cc + 4) = o1;
}

extern "C" void kernel_launch(void* const* d_in, const int* in_sizes, int n_in,
                              void* d_out, int out_size, void* d_ws, size_t ws_size,
                              hipStream_t stream) {
  (void)in_sizes; (void)n_in; (void)out_size;
  if (!d_ws || ws_size < WS_NEED) return;  // need ~481 MiB scratch

  const float* x  = (const float*)d_in[0];
  const float* rw = (const float*)d_in[1];
  const float* w1 = (const float*)d_in[2];
  const float* b1 = (const float*)d_in[3];
  const float* w2 = (const float*)d_in[4];
  const float* b2 = (const float*)d_in[5];
  float* out = (float*)d_out;

  char* ws = (char*)d_ws;
  int*       meta  = (int*)(ws + META_OFF);
  _Float16*  xb    = (_Float16*)(ws + XB_OFF);
  _Float16*  w1t   = (_Float16*)(ws + W1T_OFF);
  _Float16*  w2t   = (_Float16*)(ws + W2T_OFF);
  _Float16*  hbuf  = (_Float16*)(ws + HB_OFF);
  _Float16*  ybuf  = (_Float16*)(ws + YB_OFF);
  int*       tok   = (int*)(ws + TOK_OFF);
  float*     gate  = (float*)(ws + GATE_OFF);
  int*       tslot = (int*)(ws + TSLOT_OFF);
  int*       epair = (int*)(ws + EPAIR_OFF);
  float2*    gpair = (float2*)(ws + GPAIR_OFF);

  hipMemsetAsync(meta, 0, 256, stream);

  transpose_cast_kernel<<<dim3(F_DIM / 64, C_DIM / 64, E_NUM), 256, 0, stream>>>(w1, w1t, C_DIM, F_DIM);
  transpose_cast_kernel<<<dim3(C_DIM / 64, F_DIM / 64, E_NUM), 256, 0, stream>>>(w2, w2t, F_DIM, C_DIM);
  router_kernel<<<T_TOK / 4, 256, 0, stream>>>(x, rw, epair, gpair, xb);
  assign_kernel<<<E_NUM, 1024, 0, stream>>>(epair, gpair, meta, tok, gate, tslot);
  plan_kernel<<<1, 64, 0, stream>>>(meta);

  // max 128-row M-tiles = T*K/128 + (E-1) = 263 -> 264 (%8==0 for XCD swizzle)
  gemm1_kernel<<<264 * 16, 512, 0, stream>>>(xb, w1t, b1, hbuf, tok, meta);
  gemm2_kernel<<<264 * 4, 512, 0, stream>>>(hbuf, w2t, b2, ybuf, gate, meta);
  combine_kernel<<<(T_TOK * (C_DIM / 8)) / 256, 256, 0, stream>>>(ybuf, tslot, meta, out);
}